// Round 2
// baseline (161.945 us; speedup 1.0000x reference)
//
#include <hip/hip_runtime.h>

// MMD loss: source(4096x256 f32), target(4096x256 f32) -> scalar f32.
// 3 dispatches:
//   prep        : 256 blocks, 4 waves; each wave = 8 rows (half panel).
//                 coalesced read, bf16 cast -> LDS bounce -> coalesced packed
//                 fragment-major writes totp[panel][kq=k/8][r=row%16][8 bf16];
//                 fp32 row norms sq[8192]; per-block column partials colp
//   finalize_bw : 1 block: reduce colp + sq -> c = log2e/(16*bandwidth);
//                 also zeroes the mmd_tiles ticket counter (stream-ordered
//                 before mmd_tiles, so the poisoned ws is re-inited each iter)
//   mmd_tiles   : triangular 128x128 tiles of T*T^T; no LDS, no barriers in
//                 K-loop: register double-buffered coalesced 1KB fragment
//                 loads; SUPERTILE(8x8 tiles) ordering + XCD-contiguous
//                 swizzle; 1-exp2 epilogue; part[idx] store; LAST block
//                 (ticket: threadfence+atomicAdd) reduces part[] -> d_out
#define N_TOT 8192
#define NB    4096
#define DDIM  256
#define NTILE 64
#define NBLK  (NTILE * (NTILE + 1) / 2)   // 2080
#define PREP_BLKS 256                     // 4 waves/block, half-panel(8 rows)/wave

typedef __bf16 bf16x8 __attribute__((ext_vector_type(8)));
typedef float  f32x4  __attribute__((ext_vector_type(4)));

__device__ inline unsigned short f2bf_rne(float x) {
    unsigned int u = __float_as_uint(x);
    unsigned int r = (u + 0x7fffu + ((u >> 16) & 1u)) >> 16;
    return (unsigned short)r;
}

// ws layout (floats): [2]=c, [8]=ticket(u32), [512..8703]=sq[8192],
// [16384..18463]=part[2080], [32768..98303]=colp[256*256];
// byte 524288..: packed bf16 totp (4 MB)

__global__ __launch_bounds__(256) void prep(const float* __restrict__ src,
                                            const float* __restrict__ tgt,
                                            float* __restrict__ sq,
                                            unsigned short* __restrict__ totp,
                                            float* __restrict__ colp) {
    // per-wave half-panel buffer: 32 kq-slabs x 72 shorts (8-short pad)
    __shared__ unsigned short pbuf[4][32 * 72];
    __shared__ float cs[4 * 256];
    int t = threadIdx.x, w = t >> 6, lane = t & 63;
    int panel = blockIdx.x * 2 + (w >> 1);   // 512 panels of 16 rows
    int rhalf = w & 1;                       // which 8-row half of the panel
    int row0  = panel * 16 + rhalf * 8;

    float4 csum = {0.f, 0.f, 0.f, 0.f};
    int ls_base = (lane >> 1) * 72 + (lane & 1) * 4;   // kq-slab + e-offset
    #pragma unroll
    for (int r = 0; r < 8; ++r) {
        int row = row0 + r;
        const float* rp = (row < NB) ? (src + (size_t)row * DDIM)
                                     : (tgt + (size_t)(row - NB) * DDIM);
        float4 v = ((const float4*)rp)[lane];
        ushort4 o;
        o.x = f2bf_rne(v.x); o.y = f2bf_rne(v.y);
        o.z = f2bf_rne(v.z); o.w = f2bf_rne(v.w);
        *(ushort4*)&pbuf[w][ls_base + r * 8] = o;
        float s = v.x*v.x + v.y*v.y + v.z*v.z + v.w*v.w;
        #pragma unroll
        for (int off = 32; off > 0; off >>= 1) s += __shfl_down(s, off);
        if (lane == 0) sq[row] = s;
        csum.x += v.x; csum.y += v.y; csum.z += v.z; csum.w += v.w;
    }
    // coalesced packed writeback: 8 iters, 128B segments per 16 lanes
    #pragma unroll
    for (int it = 0; it < 8; ++it) {
        int g  = it * 256 + lane * 4;            // linear index in half-panel
        int kq = g >> 6, wi = g & 63;
        ushort4 o = *(const ushort4*)&pbuf[w][kq * 72 + wi];
        *(ushort4*)(totp + (size_t)panel * 4096 + kq * 128 + rhalf * 64 + wi) = o;
    }
    __syncthreads();                              // before reusing LDS region
    cs[w * 256 + lane * 4 + 0] = csum.x;
    cs[w * 256 + lane * 4 + 1] = csum.y;
    cs[w * 256 + lane * 4 + 2] = csum.z;
    cs[w * 256 + lane * 4 + 3] = csum.w;
    __syncthreads();
    colp[blockIdx.x * 256 + t] = (cs[t] + cs[256 + t]) + (cs[512 + t] + cs[768 + t]);
}

__global__ void finalize_bw(const float* __restrict__ colp,
                            const float* __restrict__ sq,
                            float* __restrict__ wsf) {
    __shared__ float redA[4], redB[4];
    int t = threadIdx.x, lane = t & 63, w = t >> 6;
    float a[8];
    #pragma unroll
    for (int u = 0; u < 8; ++u) a[u] = 0.f;
    for (int b = 0; b < PREP_BLKS; b += 8) {
        #pragma unroll
        for (int u = 0; u < 8; ++u) a[u] += colp[(b + u) * 256 + t];
    }
    float sv = ((a[0] + a[1]) + (a[2] + a[3])) + ((a[4] + a[5]) + (a[6] + a[7]));
    float s8[8];
    #pragma unroll
    for (int u = 0; u < 8; ++u) s8[u] = 0.f;
    for (int i = 0; i < 32; i += 8) {
        #pragma unroll
        for (int u = 0; u < 8; ++u) s8[u] += sq[(i + u) * 256 + t];
    }
    float s1 = ((s8[0] + s8[1]) + (s8[2] + s8[3])) + ((s8[4] + s8[5]) + (s8[6] + s8[7]));
    float v2 = sv * sv;
    #pragma unroll
    for (int off = 32; off > 0; off >>= 1) {
        s1 += __shfl_down(s1, off);
        v2 += __shfl_down(v2, off);
    }
    if (lane == 0) { redA[w] = s1; redB[w] = v2; }
    __syncthreads();
    if (t == 0) {
        float S1   = redA[0] + redA[1] + redA[2] + redA[3];
        float sdot = redB[0] + redB[1] + redB[2] + redB[3];
        float bw_sum = 2.0f * (float)N_TOT * S1 - 2.0f * sdot;
        double denom = (double)N_TOT * (double)N_TOT - (double)N_TOT;
        float bandwidth = (float)((double)bw_sum / denom) * 0.25f;
        wsf[2] = (1.0f / bandwidth) * 0.0625f * 1.44269504f;  // c = log2e/(16*bw)
        ((unsigned*)wsf)[8] = 0u;   // zero mmd_tiles ticket (poisoned each iter)
    }
}

__global__ __launch_bounds__(256) void mmd_tiles(const unsigned short* __restrict__ totp,
                                                 const float* __restrict__ sq,
                                                 float* __restrict__ wsf,
                                                 float* __restrict__ part,
                                                 float* __restrict__ out) {
    __shared__ float redf[4];
    __shared__ int lastf;

    // XCD-contiguous remap: XCD k (= bid%8) owns tiles [k*260, (k+1)*260)
    int idx = (blockIdx.x & 7) * 260 + (blockIdx.x >> 3);

    // supertile decode: 8x8 supertiles of 8x8 tiles, upper-triangular.
    // SI-row si holds 36 + 64*(7-si) = 484-64*si tiles.
    int si = 0, rem = idx;
    while (rem >= 484 - 64 * si) { rem -= 484 - 64 * si; ++si; }
    int ti, tj;
    if (rem < 36) {                       // diagonal supertile: 8x8 upper tri
        int li = 0, off = 0;
        while (off + (8 - li) <= rem) { off += 8 - li; ++li; }
        ti = si * 8 + li;
        tj = si * 8 + (li + rem - off);
    } else {                              // off-diagonal supertiles: full 8x8
        int r2 = rem - 36;
        tj = (si + 1 + (r2 >> 6)) * 8 + (r2 & 7);
        ti = si * 8 + ((r2 & 63) >> 3);
    }

    int t = threadIdx.x;
    int wid = t >> 6, lane = t & 63;
    int rl = lane & 15, q = lane >> 4;
    int gi0 = ti * 128, gj0 = tj * 128;
    int ia = (wid >> 1) * 64, jb = (wid & 1) * 64;

    float c = wsf[2];

    // fragment pointers: panel stride 4096 shorts, k-step stride 512 shorts
    const unsigned short* pa[4];
    const unsigned short* pb[4];
    int pA0 = (gi0 + ia) >> 4, pB0 = (gj0 + jb) >> 4;
    #pragma unroll
    for (int m = 0; m < 4; ++m) {
        pa[m] = totp + (size_t)(pA0 + m) * 4096 + lane * 8;
        pb[m] = totp + (size_t)(pB0 + m) * 4096 + lane * 8;
    }

    f32x4 acc[4][4];
    #pragma unroll
    for (int m = 0; m < 4; ++m)
        #pragma unroll
        for (int n = 0; n < 4; ++n) acc[m][n] = (f32x4){0.f, 0.f, 0.f, 0.f};

    bf16x8 av[2][4], bv[2][4];
    #pragma unroll
    for (int m = 0; m < 4; ++m) {
        av[0][m] = *(const bf16x8*)(pa[m]);
        bv[0][m] = *(const bf16x8*)(pb[m]);
    }
    #pragma unroll
    for (int s = 0; s < 8; ++s) {
        const int cur = s & 1, nxt = cur ^ 1;
        if (s < 7) {
            const int so = (s + 1) * 512;
            #pragma unroll
            for (int m = 0; m < 4; ++m) {
                av[nxt][m] = *(const bf16x8*)(pa[m] + so);
                bv[nxt][m] = *(const bf16x8*)(pb[m] + so);
            }
        }
        #pragma unroll
        for (int m = 0; m < 4; ++m)
            #pragma unroll
            for (int n = 0; n < 4; ++n)
                acc[m][n] = __builtin_amdgcn_mfma_f32_16x16x32_bf16(av[cur][m], bv[cur][n], acc[m][n], 0, 0, 0);
    }

    // epilogue: x = (2*acc - sqi - sqj)*c ; e1=2^x ; sum e1+e1^2+e1^4+e1^8+e1^16
    float tc = 2.0f * c;
    float local = 0.f;
    #pragma unroll
    for (int m = 0; m < 4; ++m) {
        f32x4 sqi = *(const f32x4*)(sq + gi0 + ia + m * 16 + q * 4);
        f32x4 ai;
        ai[0] = sqi[0] * c; ai[1] = sqi[1] * c; ai[2] = sqi[2] * c; ai[3] = sqi[3] * c;
        #pragma unroll
        for (int n = 0; n < 4; ++n) {
            float bj = sq[gj0 + jb + n * 16 + rl] * c;
            #pragma unroll
            for (int e = 0; e < 4; ++e) {
                float x  = __builtin_fmaf(acc[m][n][e], tc, -(ai[e] + bj));
                float e1 = __builtin_amdgcn_exp2f(x);
                float e2 = e1 * e1, e4 = e2 * e2, e8 = e4 * e4;
                local += ((e1 + e2) + (e4 + e8)) + e8 * e8;
            }
        }
    }
    #pragma unroll
    for (int off = 32; off > 0; off >>= 1) local += __shfl_down(local, off);
    if (lane == 0) redf[wid] = local;
    __syncthreads();
    if (t == 0) {
        float tot = redf[0] + redf[1] + redf[2] + redf[3];
        float scale = (((ti < 32) == (tj < 32)) ? 1.0f : -1.0f) * ((ti == tj) ? 1.0f : 2.0f);
        part[idx] = tot * scale;
        __threadfence();                            // release part[idx]
        unsigned old = atomicAdd((unsigned*)wsf + 8, 1u);
        lastf = (old == (unsigned)(NBLK - 1)) ? 1 : 0;
    }
    __syncthreads();
    if (lastf) {                                    // last-finishing block
        __threadfence();                            // acquire all part[]
        float s = 0.f;
        for (int i = t; i < NBLK; i += 256) s += part[i];
        #pragma unroll
        for (int off = 32; off > 0; off >>= 1) s += __shfl_down(s, off);
        if (lane == 0) redf[wid] = s;
        __syncthreads();
        if (t == 0)
            out[0] = (redf[0] + redf[1] + redf[2] + redf[3]) * (1.0f / ((float)NB * (float)NB));
    }
}

extern "C" void kernel_launch(void* const* d_in, const int* in_sizes, int n_in,
                              void* d_out, int out_size, void* d_ws, size_t ws_size,
                              hipStream_t stream) {
    const float* src = (const float*)d_in[0];
    const float* tgt = (const float*)d_in[1];
    float* wsf  = (float*)d_ws;
    float* sq   = wsf + 512;
    float* part = wsf + 16384;
    float* colp = wsf + 32768;
    unsigned short* totp = (unsigned short*)((char*)d_ws + 524288);

    prep<<<PREP_BLKS, 256, 0, stream>>>(src, tgt, sq, totp, colp);
    finalize_bw<<<1, 256, 0, stream>>>(colp, sq, wsf);
    mmd_tiles<<<NBLK, 256, 0, stream>>>(totp, sq, wsf, part, (float*)d_out);
}

// Round 3
// 110.287 us; speedup vs baseline: 1.4684x; 1.4684x over previous
//
#include <hip/hip_runtime.h>

// MMD loss: source(4096x256 f32), target(4096x256 f32) -> scalar f32.
// 4 dispatches, NO device-scope fences/tickets/atomics anywhere
// (round-2 lesson: per-block __threadfence() = L2 writeback/invalidate per
//  block on gfx950 -> 87us mmd_tiles; reverted):
//   prep        : 256 blocks, 4 waves; each wave = 8 rows (half panel).
//                 coalesced read, bf16 cast -> LDS bounce -> coalesced packed
//                 fragment-major writes totp[panel][kq=k/8][r=row%16][8 bf16];
//                 fp32 row norms sq[8192]; per-block column partials colp
//   finalize_bw : 1 block: reduce colp + sq -> c = log2e/(16*bandwidth)
//   mmd_tiles   : triangular 128x128 tiles of T*T^T; no LDS, no barriers in
//                 K-loop: register double-buffered coalesced 1KB fragment
//                 loads; SUPERTILE(8x8 tiles) ordering + XCD-contiguous
//                 swizzle; s_setprio(1) around MFMA cluster (independent
//                 waves, attn-like regime); 1-exp2 epilogue; part[idx] store
//   write_out   : 1 block: sum part[2080] -> d_out
#define N_TOT 8192
#define NB    4096
#define DDIM  256
#define NTILE 64
#define NBLK  (NTILE * (NTILE + 1) / 2)   // 2080
#define PREP_BLKS 256                     // 4 waves/block, half-panel(8 rows)/wave

typedef __bf16 bf16x8 __attribute__((ext_vector_type(8)));
typedef float  f32x4  __attribute__((ext_vector_type(4)));

__device__ inline unsigned short f2bf_rne(float x) {
    unsigned int u = __float_as_uint(x);
    unsigned int r = (u + 0x7fffu + ((u >> 16) & 1u)) >> 16;
    return (unsigned short)r;
}

// ws layout (floats): [2]=c, [512..8703]=sq[8192], [16384..18463]=part[2080],
// [32768..98303]=colp[256*256]; byte 524288..: packed bf16 totp (4 MB)

__global__ __launch_bounds__(256) void prep(const float* __restrict__ src,
                                            const float* __restrict__ tgt,
                                            float* __restrict__ sq,
                                            unsigned short* __restrict__ totp,
                                            float* __restrict__ colp) {
    // per-wave half-panel buffer: 32 kq-slabs x 72 shorts (8-short pad)
    __shared__ unsigned short pbuf[4][32 * 72];
    __shared__ float cs[4 * 256];
    int t = threadIdx.x, w = t >> 6, lane = t & 63;
    int panel = blockIdx.x * 2 + (w >> 1);   // 512 panels of 16 rows
    int rhalf = w & 1;                       // which 8-row half of the panel
    int row0  = panel * 16 + rhalf * 8;

    float4 csum = {0.f, 0.f, 0.f, 0.f};
    int ls_base = (lane >> 1) * 72 + (lane & 1) * 4;   // kq-slab + e-offset
    #pragma unroll
    for (int r = 0; r < 8; ++r) {
        int row = row0 + r;
        const float* rp = (row < NB) ? (src + (size_t)row * DDIM)
                                     : (tgt + (size_t)(row - NB) * DDIM);
        float4 v = ((const float4*)rp)[lane];
        ushort4 o;
        o.x = f2bf_rne(v.x); o.y = f2bf_rne(v.y);
        o.z = f2bf_rne(v.z); o.w = f2bf_rne(v.w);
        *(ushort4*)&pbuf[w][ls_base + r * 8] = o;
        float s = v.x*v.x + v.y*v.y + v.z*v.z + v.w*v.w;
        #pragma unroll
        for (int off = 32; off > 0; off >>= 1) s += __shfl_down(s, off);
        if (lane == 0) sq[row] = s;
        csum.x += v.x; csum.y += v.y; csum.z += v.z; csum.w += v.w;
    }
    // coalesced packed writeback: 8 iters, 128B segments per 16 lanes
    #pragma unroll
    for (int it = 0; it < 8; ++it) {
        int g  = it * 256 + lane * 4;            // linear index in half-panel
        int kq = g >> 6, wi = g & 63;
        ushort4 o = *(const ushort4*)&pbuf[w][kq * 72 + wi];
        *(ushort4*)(totp + (size_t)panel * 4096 + kq * 128 + rhalf * 64 + wi) = o;
    }
    __syncthreads();                              // before reusing LDS region
    cs[w * 256 + lane * 4 + 0] = csum.x;
    cs[w * 256 + lane * 4 + 1] = csum.y;
    cs[w * 256 + lane * 4 + 2] = csum.z;
    cs[w * 256 + lane * 4 + 3] = csum.w;
    __syncthreads();
    colp[blockIdx.x * 256 + t] = (cs[t] + cs[256 + t]) + (cs[512 + t] + cs[768 + t]);
}

__global__ void finalize_bw(const float* __restrict__ colp,
                            const float* __restrict__ sq,
                            float* __restrict__ wsf) {
    __shared__ float redA[4], redB[4];
    int t = threadIdx.x, lane = t & 63, w = t >> 6;
    float a[8];
    #pragma unroll
    for (int u = 0; u < 8; ++u) a[u] = 0.f;
    for (int b = 0; b < PREP_BLKS; b += 8) {
        #pragma unroll
        for (int u = 0; u < 8; ++u) a[u] += colp[(b + u) * 256 + t];
    }
    float sv = ((a[0] + a[1]) + (a[2] + a[3])) + ((a[4] + a[5]) + (a[6] + a[7]));
    float s8[8];
    #pragma unroll
    for (int u = 0; u < 8; ++u) s8[u] = 0.f;
    for (int i = 0; i < 32; i += 8) {
        #pragma unroll
        for (int u = 0; u < 8; ++u) s8[u] += sq[(i + u) * 256 + t];
    }
    float s1 = ((s8[0] + s8[1]) + (s8[2] + s8[3])) + ((s8[4] + s8[5]) + (s8[6] + s8[7]));
    float v2 = sv * sv;
    #pragma unroll
    for (int off = 32; off > 0; off >>= 1) {
        s1 += __shfl_down(s1, off);
        v2 += __shfl_down(v2, off);
    }
    if (lane == 0) { redA[w] = s1; redB[w] = v2; }
    __syncthreads();
    if (t == 0) {
        float S1   = redA[0] + redA[1] + redA[2] + redA[3];
        float sdot = redB[0] + redB[1] + redB[2] + redB[3];
        float bw_sum = 2.0f * (float)N_TOT * S1 - 2.0f * sdot;
        double denom = (double)N_TOT * (double)N_TOT - (double)N_TOT;
        float bandwidth = (float)((double)bw_sum / denom) * 0.25f;
        wsf[2] = (1.0f / bandwidth) * 0.0625f * 1.44269504f;  // c = log2e/(16*bw)
    }
}

__global__ __launch_bounds__(256) void mmd_tiles(const unsigned short* __restrict__ totp,
                                                 const float* __restrict__ sq,
                                                 const float* __restrict__ wsf,
                                                 float* __restrict__ part) {
    __shared__ float redf[4];

    // XCD-contiguous remap: XCD k (= bid%8) owns tiles [k*260, (k+1)*260)
    int idx = (blockIdx.x & 7) * 260 + (blockIdx.x >> 3);

    // supertile decode: 8x8 supertiles of 8x8 tiles, upper-triangular.
    // SI-row si holds 36 + 64*(7-si) = 484-64*si tiles.
    int si = 0, rem = idx;
    while (rem >= 484 - 64 * si) { rem -= 484 - 64 * si; ++si; }
    int ti, tj;
    if (rem < 36) {                       // diagonal supertile: 8x8 upper tri
        int li = 0, off = 0;
        while (off + (8 - li) <= rem) { off += 8 - li; ++li; }
        ti = si * 8 + li;
        tj = si * 8 + (li + rem - off);
    } else {                              // off-diagonal supertiles: full 8x8
        int r2 = rem - 36;
        tj = (si + 1 + (r2 >> 6)) * 8 + (r2 & 7);
        ti = si * 8 + ((r2 & 63) >> 3);
    }

    int t = threadIdx.x;
    int wid = t >> 6, lane = t & 63;
    int rl = lane & 15, q = lane >> 4;
    int gi0 = ti * 128, gj0 = tj * 128;
    int ia = (wid >> 1) * 64, jb = (wid & 1) * 64;

    float c = wsf[2];

    // fragment pointers: panel stride 4096 shorts, k-step stride 512 shorts
    const unsigned short* pa[4];
    const unsigned short* pb[4];
    int pA0 = (gi0 + ia) >> 4, pB0 = (gj0 + jb) >> 4;
    #pragma unroll
    for (int m = 0; m < 4; ++m) {
        pa[m] = totp + (size_t)(pA0 + m) * 4096 + lane * 8;
        pb[m] = totp + (size_t)(pB0 + m) * 4096 + lane * 8;
    }

    f32x4 acc[4][4];
    #pragma unroll
    for (int m = 0; m < 4; ++m)
        #pragma unroll
        for (int n = 0; n < 4; ++n) acc[m][n] = (f32x4){0.f, 0.f, 0.f, 0.f};

    bf16x8 av[2][4], bv[2][4];
    #pragma unroll
    for (int m = 0; m < 4; ++m) {
        av[0][m] = *(const bf16x8*)(pa[m]);
        bv[0][m] = *(const bf16x8*)(pb[m]);
    }
    #pragma unroll
    for (int s = 0; s < 8; ++s) {
        const int cur = s & 1, nxt = cur ^ 1;
        if (s < 7) {
            const int so = (s + 1) * 512;
            #pragma unroll
            for (int m = 0; m < 4; ++m) {
                av[nxt][m] = *(const bf16x8*)(pa[m] + so);
                bv[nxt][m] = *(const bf16x8*)(pb[m] + so);
            }
        }
        __builtin_amdgcn_s_setprio(1);
        #pragma unroll
        for (int m = 0; m < 4; ++m)
            #pragma unroll
            for (int n = 0; n < 4; ++n)
                acc[m][n] = __builtin_amdgcn_mfma_f32_16x16x32_bf16(av[cur][m], bv[cur][n], acc[m][n], 0, 0, 0);
        __builtin_amdgcn_s_setprio(0);
    }

    // epilogue: x = (2*acc - sqi - sqj)*c ; e1=2^x ; sum e1+e1^2+e1^4+e1^8+e1^16
    float tc = 2.0f * c;
    float local = 0.f;
    #pragma unroll
    for (int m = 0; m < 4; ++m) {
        f32x4 sqi = *(const f32x4*)(sq + gi0 + ia + m * 16 + q * 4);
        f32x4 ai;
        ai[0] = sqi[0] * c; ai[1] = sqi[1] * c; ai[2] = sqi[2] * c; ai[3] = sqi[3] * c;
        #pragma unroll
        for (int n = 0; n < 4; ++n) {
            float bj = sq[gj0 + jb + n * 16 + rl] * c;
            #pragma unroll
            for (int e = 0; e < 4; ++e) {
                float x  = __builtin_fmaf(acc[m][n][e], tc, -(ai[e] + bj));
                float e1 = __builtin_amdgcn_exp2f(x);
                float e2 = e1 * e1, e4 = e2 * e2, e8 = e4 * e4;
                local += ((e1 + e2) + (e4 + e8)) + e8 * e8;
            }
        }
    }
    #pragma unroll
    for (int off = 32; off > 0; off >>= 1) local += __shfl_down(local, off);
    if (lane == 0) redf[wid] = local;
    __syncthreads();
    if (t == 0) {
        float tot = redf[0] + redf[1] + redf[2] + redf[3];
        float scale = (((ti < 32) == (tj < 32)) ? 1.0f : -1.0f) * ((ti == tj) ? 1.0f : 2.0f);
        part[idx] = tot * scale;
    }
}

__global__ void write_out(const float* __restrict__ part, float* __restrict__ out) {
    __shared__ float red[4];
    int t = threadIdx.x, lane = t & 63, w = t >> 6;
    float s = 0.f;
    for (int i = t; i < NBLK; i += 256) s += part[i];
    #pragma unroll
    for (int off = 32; off > 0; off >>= 1) s += __shfl_down(s, off);
    if (lane == 0) red[w] = s;
    __syncthreads();
    if (t == 0)
        out[0] = (red[0] + red[1] + red[2] + red[3]) * (1.0f / ((float)NB * (float)NB));
}

extern "C" void kernel_launch(void* const* d_in, const int* in_sizes, int n_in,
                              void* d_out, int out_size, void* d_ws, size_t ws_size,
                              hipStream_t stream) {
    const float* src = (const float*)d_in[0];
    const float* tgt = (const float*)d_in[1];
    float* wsf  = (float*)d_ws;
    float* sq   = wsf + 512;
    float* part = wsf + 16384;
    float* colp = wsf + 32768;
    unsigned short* totp = (unsigned short*)((char*)d_ws + 524288);

    prep<<<PREP_BLKS, 256, 0, stream>>>(src, tgt, sq, totp, colp);
    finalize_bw<<<1, 256, 0, stream>>>(colp, sq, wsf);
    mmd_tiles<<<NBLK, 256, 0, stream>>>(totp, sq, wsf, part);
    write_out<<<1, 256, 0, stream>>>(part, (float*)d_out);
}

// Round 4
// 104.072 us; speedup vs baseline: 1.5561x; 1.0597x over previous
//
#include <hip/hip_runtime.h>

// MMD loss: source(4096x256 f32), target(4096x256 f32) -> scalar f32.
// 4 dispatches, NO device-scope fences/tickets/atomics anywhere
// (round-2 lesson: per-block __threadfence() = L2 writeback/invalidate per
//  block on gfx950 -> 87us mmd_tiles; reverted):
//   prep        : 256 blocks, 4 waves; each wave = 8 rows (half panel).
//   finalize_bw : 1 block: reduce colp + sq -> c = log2e/(16*bandwidth)
//   mmd_tiles   : triangular 128x128 tiles of T*T^T; VALU-bound (round-2
//                 counters: VALU-busy ~13.8us vs MFMA ~6.6us) -> epilogue
//                 rewritten in f32x2 packed ops (v_pk_*_f32, full-rate on
//                 CDNA4) + bj*c hoisted; register double-buffered K-loop,
//                 supertile ordering + XCD swizzle; setprio around MFMA
//   write_out   : 1 block: sum part[2080] -> d_out
#define N_TOT 8192
#define NB    4096
#define DDIM  256
#define NTILE 64
#define NBLK  (NTILE * (NTILE + 1) / 2)   // 2080
#define PREP_BLKS 256                     // 4 waves/block, half-panel(8 rows)/wave

typedef __bf16 bf16x8 __attribute__((ext_vector_type(8)));
typedef float  f32x4  __attribute__((ext_vector_type(4)));
typedef float  f32x2  __attribute__((ext_vector_type(2)));

__device__ inline unsigned short f2bf_rne(float x) {
    unsigned int u = __float_as_uint(x);
    unsigned int r = (u + 0x7fffu + ((u >> 16) & 1u)) >> 16;
    return (unsigned short)r;
}

// ws layout (floats): [2]=c, [512..8703]=sq[8192], [16384..18463]=part[2080],
// [32768..98303]=colp[256*256]; byte 524288..: packed bf16 totp (4 MB)

__global__ __launch_bounds__(256) void prep(const float* __restrict__ src,
                                            const float* __restrict__ tgt,
                                            float* __restrict__ sq,
                                            unsigned short* __restrict__ totp,
                                            float* __restrict__ colp) {
    // per-wave half-panel buffer: 32 kq-slabs x 72 shorts (8-short pad)
    __shared__ unsigned short pbuf[4][32 * 72];
    __shared__ float cs[4 * 256];
    int t = threadIdx.x, w = t >> 6, lane = t & 63;
    int panel = blockIdx.x * 2 + (w >> 1);   // 512 panels of 16 rows
    int rhalf = w & 1;                       // which 8-row half of the panel
    int row0  = panel * 16 + rhalf * 8;

    float4 csum = {0.f, 0.f, 0.f, 0.f};
    int ls_base = (lane >> 1) * 72 + (lane & 1) * 4;   // kq-slab + e-offset
    #pragma unroll
    for (int r = 0; r < 8; ++r) {
        int row = row0 + r;
        const float* rp = (row < NB) ? (src + (size_t)row * DDIM)
                                     : (tgt + (size_t)(row - NB) * DDIM);
        float4 v = ((const float4*)rp)[lane];
        ushort4 o;
        o.x = f2bf_rne(v.x); o.y = f2bf_rne(v.y);
        o.z = f2bf_rne(v.z); o.w = f2bf_rne(v.w);
        *(ushort4*)&pbuf[w][ls_base + r * 8] = o;
        float s = v.x*v.x + v.y*v.y + v.z*v.z + v.w*v.w;
        #pragma unroll
        for (int off = 32; off > 0; off >>= 1) s += __shfl_down(s, off);
        if (lane == 0) sq[row] = s;
        csum.x += v.x; csum.y += v.y; csum.z += v.z; csum.w += v.w;
    }
    // coalesced packed writeback: 8 iters, 128B segments per 16 lanes
    #pragma unroll
    for (int it = 0; it < 8; ++it) {
        int g  = it * 256 + lane * 4;            // linear index in half-panel
        int kq = g >> 6, wi = g & 63;
        ushort4 o = *(const ushort4*)&pbuf[w][kq * 72 + wi];
        *(ushort4*)(totp + (size_t)panel * 4096 + kq * 128 + rhalf * 64 + wi) = o;
    }
    __syncthreads();                              // before reusing LDS region
    cs[w * 256 + lane * 4 + 0] = csum.x;
    cs[w * 256 + lane * 4 + 1] = csum.y;
    cs[w * 256 + lane * 4 + 2] = csum.z;
    cs[w * 256 + lane * 4 + 3] = csum.w;
    __syncthreads();
    colp[blockIdx.x * 256 + t] = (cs[t] + cs[256 + t]) + (cs[512 + t] + cs[768 + t]);
}

__global__ void finalize_bw(const float* __restrict__ colp,
                            const float* __restrict__ sq,
                            float* __restrict__ wsf) {
    __shared__ float redA[4], redB[4];
    int t = threadIdx.x, lane = t & 63, w = t >> 6;
    float a[8];
    #pragma unroll
    for (int u = 0; u < 8; ++u) a[u] = 0.f;
    for (int b = 0; b < PREP_BLKS; b += 8) {
        #pragma unroll
        for (int u = 0; u < 8; ++u) a[u] += colp[(b + u) * 256 + t];
    }
    float sv = ((a[0] + a[1]) + (a[2] + a[3])) + ((a[4] + a[5]) + (a[6] + a[7]));
    float s8[8];
    #pragma unroll
    for (int u = 0; u < 8; ++u) s8[u] = 0.f;
    for (int i = 0; i < 32; i += 8) {
        #pragma unroll
        for (int u = 0; u < 8; ++u) s8[u] += sq[(i + u) * 256 + t];
    }
    float s1 = ((s8[0] + s8[1]) + (s8[2] + s8[3])) + ((s8[4] + s8[5]) + (s8[6] + s8[7]));
    float v2 = sv * sv;
    #pragma unroll
    for (int off = 32; off > 0; off >>= 1) {
        s1 += __shfl_down(s1, off);
        v2 += __shfl_down(v2, off);
    }
    if (lane == 0) { redA[w] = s1; redB[w] = v2; }
    __syncthreads();
    if (t == 0) {
        float S1   = redA[0] + redA[1] + redA[2] + redA[3];
        float sdot = redB[0] + redB[1] + redB[2] + redB[3];
        float bw_sum = 2.0f * (float)N_TOT * S1 - 2.0f * sdot;
        double denom = (double)N_TOT * (double)N_TOT - (double)N_TOT;
        float bandwidth = (float)((double)bw_sum / denom) * 0.25f;
        wsf[2] = (1.0f / bandwidth) * 0.0625f * 1.44269504f;  // c = log2e/(16*bw)
    }
}

__global__ __launch_bounds__(256) void mmd_tiles(const unsigned short* __restrict__ totp,
                                                 const float* __restrict__ sq,
                                                 const float* __restrict__ wsf,
                                                 float* __restrict__ part) {
    __shared__ float redf[4];

    // XCD-contiguous remap: XCD k (= bid%8) owns tiles [k*260, (k+1)*260)
    int idx = (blockIdx.x & 7) * 260 + (blockIdx.x >> 3);

    // supertile decode: 8x8 supertiles of 8x8 tiles, upper-triangular.
    // SI-row si holds 36 + 64*(7-si) = 484-64*si tiles.
    int si = 0, rem = idx;
    while (rem >= 484 - 64 * si) { rem -= 484 - 64 * si; ++si; }
    int ti, tj;
    if (rem < 36) {                       // diagonal supertile: 8x8 upper tri
        int li = 0, off = 0;
        while (off + (8 - li) <= rem) { off += 8 - li; ++li; }
        ti = si * 8 + li;
        tj = si * 8 + (li + rem - off);
    } else {                              // off-diagonal supertiles: full 8x8
        int r2 = rem - 36;
        tj = (si + 1 + (r2 >> 6)) * 8 + (r2 & 7);
        ti = si * 8 + ((r2 & 63) >> 3);
    }

    int t = threadIdx.x;
    int wid = t >> 6, lane = t & 63;
    int rl = lane & 15, q = lane >> 4;
    int gi0 = ti * 128, gj0 = tj * 128;
    int ia = (wid >> 1) * 64, jb = (wid & 1) * 64;

    float c = wsf[2];

    // fragment pointers: panel stride 4096 shorts, k-step stride 512 shorts
    const unsigned short* pa[4];
    const unsigned short* pb[4];
    int pA0 = (gi0 + ia) >> 4, pB0 = (gj0 + jb) >> 4;
    #pragma unroll
    for (int m = 0; m < 4; ++m) {
        pa[m] = totp + (size_t)(pA0 + m) * 4096 + lane * 8;
        pb[m] = totp + (size_t)(pB0 + m) * 4096 + lane * 8;
    }

    f32x4 acc[4][4];
    #pragma unroll
    for (int m = 0; m < 4; ++m)
        #pragma unroll
        for (int n = 0; n < 4; ++n) acc[m][n] = (f32x4){0.f, 0.f, 0.f, 0.f};

    bf16x8 av[2][4], bv[2][4];
    #pragma unroll
    for (int m = 0; m < 4; ++m) {
        av[0][m] = *(const bf16x8*)(pa[m]);
        bv[0][m] = *(const bf16x8*)(pb[m]);
    }
    #pragma unroll
    for (int s = 0; s < 8; ++s) {
        const int cur = s & 1, nxt = cur ^ 1;
        if (s < 7) {
            const int so = (s + 1) * 512;
            #pragma unroll
            for (int m = 0; m < 4; ++m) {
                av[nxt][m] = *(const bf16x8*)(pa[m] + so);
                bv[nxt][m] = *(const bf16x8*)(pb[m] + so);
            }
        }
        __builtin_amdgcn_s_setprio(1);
        #pragma unroll
        for (int m = 0; m < 4; ++m)
            #pragma unroll
            for (int n = 0; n < 4; ++n)
                acc[m][n] = __builtin_amdgcn_mfma_f32_16x16x32_bf16(av[cur][m], bv[cur][n], acc[m][n], 0, 0, 0);
        __builtin_amdgcn_s_setprio(0);
    }

    // epilogue (packed f32x2 -> v_pk_*_f32):
    // x = (2*acc - sqi - sqj)*c ; e1=2^x ; sum e1+e1^2+e1^4+e1^8+e1^16
    const f32x2 tc2 = {2.0f * c, 2.0f * c};
    f32x2 lacc = {0.f, 0.f};
    float bjc[4];
    #pragma unroll
    for (int n = 0; n < 4; ++n) bjc[n] = sq[gj0 + jb + n * 16 + rl] * c;
    #pragma unroll
    for (int m = 0; m < 4; ++m) {
        f32x4 sqi = *(const f32x4*)(sq + gi0 + ia + m * 16 + q * 4);
        f32x2 ai0; ai0[0] = sqi[0] * c; ai0[1] = sqi[1] * c;
        f32x2 ai1; ai1[0] = sqi[2] * c; ai1[1] = sqi[3] * c;
        #pragma unroll
        for (int n = 0; n < 4; ++n) {
            f32x2 bj2; bj2[0] = bjc[n]; bj2[1] = bjc[n];
            f32x2 aib0 = ai0 + bj2, aib1 = ai1 + bj2;
            f32x2 d0; d0[0] = acc[m][n][0]; d0[1] = acc[m][n][1];
            f32x2 d1; d1[0] = acc[m][n][2]; d1[1] = acc[m][n][3];
            f32x2 x0 = d0 * tc2 - aib0;
            f32x2 x1 = d1 * tc2 - aib1;
            f32x2 e1a, e1b;
            e1a[0] = __builtin_amdgcn_exp2f(x0[0]);
            e1a[1] = __builtin_amdgcn_exp2f(x0[1]);
            e1b[0] = __builtin_amdgcn_exp2f(x1[0]);
            e1b[1] = __builtin_amdgcn_exp2f(x1[1]);
            f32x2 e2a = e1a * e1a, e4a = e2a * e2a, e8a = e4a * e4a;
            f32x2 e2b = e1b * e1b, e4b = e2b * e2b, e8b = e4b * e4b;
            lacc += ((e1a + e2a) + (e4a + e8a)) + e8a * e8a;
            lacc += ((e1b + e2b) + (e4b + e8b)) + e8b * e8b;
        }
    }
    float local = lacc[0] + lacc[1];
    #pragma unroll
    for (int off = 32; off > 0; off >>= 1) local += __shfl_down(local, off);
    if (lane == 0) redf[wid] = local;
    __syncthreads();
    if (t == 0) {
        float tot = redf[0] + redf[1] + redf[2] + redf[3];
        float scale = (((ti < 32) == (tj < 32)) ? 1.0f : -1.0f) * ((ti == tj) ? 1.0f : 2.0f);
        part[idx] = tot * scale;
    }
}

__global__ void write_out(const float* __restrict__ part, float* __restrict__ out) {
    __shared__ float red[4];
    int t = threadIdx.x, lane = t & 63, w = t >> 6;
    float s = 0.f;
    for (int i = t; i < NBLK; i += 256) s += part[i];
    #pragma unroll
    for (int off = 32; off > 0; off >>= 1) s += __shfl_down(s, off);
    if (lane == 0) red[w] = s;
    __syncthreads();
    if (t == 0)
        out[0] = (red[0] + red[1] + red[2] + red[3]) * (1.0f / ((float)NB * (float)NB));
}

extern "C" void kernel_launch(void* const* d_in, const int* in_sizes, int n_in,
                              void* d_out, int out_size, void* d_ws, size_t ws_size,
                              hipStream_t stream) {
    const float* src = (const float*)d_in[0];
    const float* tgt = (const float*)d_in[1];
    float* wsf  = (float*)d_ws;
    float* sq   = wsf + 512;
    float* part = wsf + 16384;
    float* colp = wsf + 32768;
    unsigned short* totp = (unsigned short*)((char*)d_ws + 524288);

    prep<<<PREP_BLKS, 256, 0, stream>>>(src, tgt, sq, totp, colp);
    finalize_bw<<<1, 256, 0, stream>>>(colp, sq, wsf);
    mmd_tiles<<<NBLK, 256, 0, stream>>>(totp, sq, wsf, part);
    write_out<<<1, 256, 0, stream>>>(part, (float*)d_out);
}